// Round 8
// baseline (1169.374 us; speedup 1.0000x reference)
//
#include <hip/hip_runtime.h>

// GIN: N=50000, E=800000, C=64/128/64, fp32 in/out.
//
// Round 17: edge-parallel gather with LDS f32 atomic accumulation.
// R14 (L2-resident: no gain), R15 (2x ILP: no gain), R16 (1/2 requests:
// no gain) killed every locality/rate hypothesis. Remaining: the per-node
// serial loop (dependent index->gather chain + wave divergence at
// max-of-8 Poisson degrees). Fix: csr is dst-sorted and a block's edges
// are contiguous and all target its 64 nodes -> iterate EDGES:
// 512 threads = 64 edges/iter x 8 threads x 32B (contiguous), accumulate
// via atomicAdd into LDS f32 (ds_add_f32: no return, no dependent wait,
// iterations independent -> deep natural pipelining, zero divergence).
// pass2 now also emits 8-bit bucket-local dst per edge. Accumulator
// [64][132] f32 (+pad: ds_add banks ld*4+ch ~2-way = free) aliased as
// bf16 staging after a reg-hold/barrier/convert. MFMA tails unchanged.

using bf16x8 = __attribute__((ext_vector_type(8))) short;
using f32x4 = __attribute__((ext_vector_type(4))) float;

static __device__ __forceinline__ unsigned short f2bf(float f) {
  unsigned int u = __builtin_bit_cast(unsigned int, f);
  u += 0x7fff + ((u >> 16) & 1);  // RNE
  return (unsigned short)(u >> 16);
}
static __device__ __forceinline__ float lo2f(unsigned int u) {
  return __builtin_bit_cast(float, u << 16);
}
static __device__ __forceinline__ float hi2f(unsigned int u) {
  return __builtin_bit_cast(float, u & 0xffff0000u);
}
static __device__ __forceinline__ unsigned int pack2(float lo, float hi) {
  return (unsigned int)f2bf(lo) | ((unsigned int)f2bf(hi) << 16);
}

// ---------------- prep: x->bf16 | W->bf16 transposed | bcnt zero -----------
__global__ __launch_bounds__(256) void prep_kernel(
    const float* __restrict__ x, unsigned short* __restrict__ xb, int n4,
    const float* __restrict__ W1, const float* __restrict__ W2,
    const float* __restrict__ W3, const float* __restrict__ W4,
    unsigned short* __restrict__ W1t, unsigned short* __restrict__ W2t,
    unsigned short* __restrict__ W3t, unsigned short* __restrict__ W4t,
    int* __restrict__ bcnt, int nxb) {
  const int b = blockIdx.x;
  const int tid = threadIdx.x;
  if (b < nxb) {
    int i = b * 256 + tid;
    if (i < n4) {
      float4 v = ((const float4*)x)[i];
      ushort4 o;
      o.x = f2bf(v.x);
      o.y = f2bf(v.y);
      o.z = f2bf(v.z);
      o.w = f2bf(v.w);
      ((ushort4*)xb)[i] = o;
    }
  } else if (b < nxb + 192) {
    int i = (b - nxb) * 256 + tid;
    if (i < 8192) {
      int n = i >> 6, k = i & 63;
      W1t[i] = f2bf(W1[k * 128 + n]);
    } else if (i < 24576) {
      int j = i - 8192;
      int n = j >> 7, k = j & 127;
      W2t[j] = f2bf(W2[k * 128 + n]);
    } else if (i < 40960) {
      int j = i - 24576;
      int n = j >> 7, k = j & 127;
      W3t[j] = f2bf(W3[k * 128 + n]);
    } else if (i < 49152) {
      int j = i - 40960;
      int n = j >> 7, k = j & 127;
      W4t[j] = f2bf(W4[k * 64 + n]);
    }
  } else {
    bcnt[tid] = 0;
  }
}

// ---------------- bucketed CSR build ----------------

__global__ __launch_bounds__(256) void bhist_kernel(const int* __restrict__ ei,
                                                    int* __restrict__ bcnt,
                                                    int E_, int nbkt) {
  __shared__ int h[256];
  const int tid = threadIdx.x;
  h[tid] = 0;
  __syncthreads();
#pragma unroll
  for (int i = 0; i < 4; ++i) {
    int e = blockIdx.x * 1024 + i * 256 + tid;
    if (e < E_) atomicAdd(&h[ei[E_ + e] >> 8], 1);
  }
  __syncthreads();
  if (tid < nbkt && h[tid] > 0) atomicAdd(&bcnt[tid], h[tid]);
}

__global__ __launch_bounds__(256) void bscan_kernel(
    const int* __restrict__ bcnt, int* __restrict__ bbase,
    int* __restrict__ bcur, int nbkt, int E_) {
  __shared__ int s[256];
  const int tid = threadIdx.x;
  const int v = (tid < nbkt) ? bcnt[tid] : 0;
  s[tid] = v;
  __syncthreads();
  for (int off = 1; off < 256; off <<= 1) {
    int u = (tid >= off) ? s[tid - off] : 0;
    __syncthreads();
    s[tid] += u;
    __syncthreads();
  }
  int excl = s[tid] - v;
  if (tid < nbkt) {
    bbase[tid] = excl;
    bcur[tid] = excl;
  }
  if (tid == 0) bbase[nbkt] = E_;
}

// pass 1: 4096 edges/block, 512 threads (8 edges/thread).
// packed word = (bin<<24) | (local_dst<<16) | src   (src < 65536)
__global__ __launch_bounds__(512) void pass1_kernel(
    const int* __restrict__ ei, int* __restrict__ bcur,
    unsigned int* __restrict__ packed, int E_, int nbkt) {
  __shared__ int hist[256];
  __shared__ int off[256];
  __shared__ int cur[256];
  __shared__ int cb[256];
  __shared__ unsigned int pk[4096];
  const int tid = threadIdx.x;
  const int e0 = blockIdx.x * 4096;

  if (tid < 256) hist[tid] = 0;
  __syncthreads();

  int myd[8];
#pragma unroll
  for (int i = 0; i < 8; ++i) {
    int e = e0 + i * 512 + tid;
    myd[i] = -1;
    if (e < E_) {
      int d = ei[E_ + e];
      myd[i] = d;
      atomicAdd(&hist[d >> 8], 1);
    }
  }
  __syncthreads();

  int hval = 0;
  if (tid < 256) {
    hval = hist[tid];
    off[tid] = hval;
  }
  __syncthreads();
  for (int o = 1; o < 256; o <<= 1) {
    int u = 0;
    if (tid < 256 && tid >= o) u = off[tid - o];
    __syncthreads();
    if (tid < 256) off[tid] += u;
    __syncthreads();
  }
  int excl = 0;
  if (tid < 256) excl = off[tid] - hval;
  __syncthreads();
  if (tid < 256) {
    off[tid] = excl;
    cur[tid] = excl;
    if (tid < nbkt && hval > 0) cb[tid] = atomicAdd(&bcur[tid], hval);
  }
  __syncthreads();

#pragma unroll
  for (int i = 0; i < 8; ++i) {
    int e = e0 + i * 512 + tid;
    if (e < E_) {
      int d = myd[i];
      int bin = d >> 8;
      unsigned int w = ((unsigned int)bin << 24) |
                       ((unsigned int)(d & 255) << 16) | (unsigned int)ei[e];
      int p = atomicAdd(&cur[bin], 1);
      pk[p] = w;
    }
  }
  __syncthreads();

  const int nval = min(4096, E_ - e0);
#pragma unroll
  for (int i = 0; i < 8; ++i) {
    int idx = i * 512 + tid;
    if (idx < nval) {
      unsigned int w = pk[idx];
      int bin = w >> 24;
      packed[cb[bin] + (idx - off[bin])] = w;
    }
  }
}

// pass 2: quarter-bucket blocks (nbkt*4), 256 threads.
// Emits csr_src (src) AND csr_ldst (8-bit bucket-local dst) per edge.
#define P2CAP 2048
__global__ __launch_bounds__(256) void pass2_kernel(
    const unsigned int* __restrict__ packed, const int* __restrict__ bbase,
    int* __restrict__ row_off, int* __restrict__ csr_src,
    unsigned char* __restrict__ csr_ldst, int Nn, int E_, int nbkt) {
  __shared__ int hist[256];
  __shared__ int sc[256];
  __shared__ int cur[256];
  __shared__ int lsrc[P2CAP];
  const int tid = threadIdx.x;
  const int b = blockIdx.x >> 2;
  const int q = blockIdx.x & 3;
  const int beg = bbase[b], end = bbase[b + 1];
  const int cnt = end - beg;
  const int myLo = q * 64, myHi = myLo + 64;

  hist[tid] = 0;
  __syncthreads();
  for (int idx = tid; idx < cnt; idx += 256)
    atomicAdd(&hist[(packed[beg + idx] >> 16) & 255], 1);
  __syncthreads();

  const int hval = hist[tid];
  sc[tid] = hval;
  __syncthreads();
  for (int o = 1; o < 256; o <<= 1) {
    int u = (tid >= o) ? sc[tid - o] : 0;
    __syncthreads();
    sc[tid] += u;
    __syncthreads();
  }
  __syncthreads();
  const int qStart = (myLo == 0) ? 0 : sc[myLo - 1];
  const int qEnd = sc[myHi - 1];
  if (tid >= myLo && tid < myHi) {
    const int excl = sc[tid] - hval;
    cur[tid] = excl - qStart;
    const int node = b * 256 + tid;
    if (node < Nn) row_off[node] = beg + excl;
  }
  if (b == nbkt - 1 && q == 3 && tid == 0) row_off[Nn] = E_;
  __syncthreads();

  for (int idx = tid; idx < cnt; idx += 256) {
    unsigned int w = packed[beg + idx];
    int ldst = (w >> 16) & 255;
    if (ldst >= myLo && ldst < myHi) {
      int p = atomicAdd(&cur[ldst], 1);
      if (p < P2CAP) lsrc[p] = (int)(w & 0xffffffu);  // (ldst<<16)|src
    }
  }
  __syncthreads();

  const int myCnt = min(qEnd - qStart, P2CAP);
  for (int idx = tid; idx < myCnt; idx += 256) {
    int v = lsrc[idx];
    csr_src[beg + qStart + idx] = v & 0xffff;
    csr_ldst[beg + qStart + idx] = (unsigned char)(v >> 16);
  }
}

// ---------------- fused edge-parallel gather + MFMA MLPs (512 thr) --------
// MFMA maps (mfma_f32_16x16x32_bf16):
//   A: lane holds A[m=lane&15][k=(lane>>4)*8+j];  B: B[k=...][n=lane&15]
//   C/D: col=lane&15, row=(lane>>4)*4+reg
// Wave w of 8: m0=(w&3)*16, n-half = w>>2.

__global__ __launch_bounds__(512) void gmlp1_kernel(
    const unsigned short* __restrict__ xb, const int* __restrict__ row_off,
    const int* __restrict__ csr_src, const unsigned char* __restrict__ csr_ldst,
    const unsigned short* __restrict__ W1t, const float* __restrict__ b1,
    const unsigned short* __restrict__ W2t, const float* __restrict__ b2,
    unsigned short* __restrict__ hb, int Nn) {
  // A1f [64][68] f32 (pad +4: ds_add bank spread ld*4+ch). After the
  // gather it is converted IN PLACE (reg-hold/barrier) to bf16 rows of
  // stride 136 ushort (= 272B = same row bytes).
  __shared__ __align__(16) float A1f[64][68];
  __shared__ __align__(16) unsigned short Z[64][136];
  unsigned short* A1 = (unsigned short*)&A1f[0][0];
  const int tid = threadIdx.x;
  const int bm = blockIdx.x * 64;
  const int ln = tid >> 3;
  const int cl = tid & 7;

  {  // init accumulator with the node's own row (GIN: x + sum)
    const int node = bm + ln;
    uint4 v = {0, 0, 0, 0};
    if (node < Nn) v = ((const uint4*)(xb + (size_t)node * 64))[cl];
    float* dst = &A1f[ln][cl * 8];
    dst[0] = lo2f(v.x); dst[1] = hi2f(v.x);
    dst[2] = lo2f(v.y); dst[3] = hi2f(v.y);
    dst[4] = lo2f(v.z); dst[5] = hi2f(v.z);
    dst[6] = lo2f(v.w); dst[7] = hi2f(v.w);
  }
  const int beg = row_off[bm];
  const int end = row_off[(bm + 64) < Nn ? (bm + 64) : Nn];
  __syncthreads();

  const int ldoff = bm & 255;
  const int eslot = tid >> 3;
  // edge-parallel: 64 edges per iteration, 8 threads x 16B per edge.
  // Iterations independent (ds_add_f32 has no return) -> deep pipeline.
#pragma unroll 2
  for (int e = beg + eslot; e < end; e += 64) {
    int src = csr_src[e];
    int ld = (int)csr_ldst[e] - ldoff;
    uint4 u = ((const uint4*)(xb + (size_t)src * 64))[cl];
    float* ap = &A1f[ld][cl * 8];
    atomicAdd(ap + 0, lo2f(u.x)); atomicAdd(ap + 1, hi2f(u.x));
    atomicAdd(ap + 2, lo2f(u.y)); atomicAdd(ap + 3, hi2f(u.y));
    atomicAdd(ap + 4, lo2f(u.z)); atomicAdd(ap + 5, hi2f(u.z));
    atomicAdd(ap + 6, lo2f(u.w)); atomicAdd(ap + 7, hi2f(u.w));
  }
  __syncthreads();

  {  // convert f32 -> bf16 in place (reg-hold, barrier, store)
    float t0[8];
    const float* sp = &A1f[ln][cl * 8];
#pragma unroll
    for (int i = 0; i < 8; ++i) t0[i] = sp[i];
    __syncthreads();
    unsigned short* dp = A1 + ln * 136 + cl * 8;
#pragma unroll
    for (int i = 0; i < 8; ++i) dp[i] = f2bf(t0[i]);
  }
  __syncthreads();

  const int lane = tid & 63;
  const int wv = tid >> 6;
  const int m0 = (wv & 3) * 16;
  const int nbase = (wv >> 2) * 64;
  const int lm = lane & 15, lq = lane >> 4;

  bf16x8 a0 = *(const bf16x8*)(A1 + (m0 + lm) * 136 + lq * 8);
  bf16x8 a1 = *(const bf16x8*)(A1 + (m0 + lm) * 136 + 32 + lq * 8);
#pragma unroll
  for (int ntl = 0; ntl < 4; ++ntl) {
    const int n = nbase + ntl * 16 + lm;
    bf16x8 w0 = *(const bf16x8*)(W1t + n * 64 + lq * 8);
    bf16x8 w1 = *(const bf16x8*)(W1t + n * 64 + 32 + lq * 8);
    f32x4 acc = {0.f, 0.f, 0.f, 0.f};
    acc = __builtin_amdgcn_mfma_f32_16x16x32_bf16(a0, w0, acc, 0, 0, 0);
    acc = __builtin_amdgcn_mfma_f32_16x16x32_bf16(a1, w1, acc, 0, 0, 0);
    const float bias = b1[n];
#pragma unroll
    for (int r = 0; r < 4; ++r) {
      float z = acc[r] + bias;
      z = z > 0.f ? z : 0.f;
      Z[m0 + lq * 4 + r][n] = f2bf(z);
    }
  }
  __syncthreads();

  bf16x8 za[4];
#pragma unroll
  for (int kt = 0; kt < 4; ++kt)
    za[kt] = *(const bf16x8*)&Z[m0 + lm][kt * 32 + lq * 8];
#pragma unroll
  for (int ntl = 0; ntl < 4; ++ntl) {
    const int n = nbase + ntl * 16 + lm;
    f32x4 acc = {0.f, 0.f, 0.f, 0.f};
#pragma unroll
    for (int kt = 0; kt < 4; ++kt) {
      bf16x8 w = *(const bf16x8*)(W2t + n * 128 + kt * 32 + lq * 8);
      acc = __builtin_amdgcn_mfma_f32_16x16x32_bf16(za[kt], w, acc, 0, 0, 0);
    }
    const float bias = b2[n];
#pragma unroll
    for (int r = 0; r < 4; ++r) {
      float z = acc[r] + bias;
      z = z > 0.f ? z : 0.f;
      int gm = bm + m0 + lq * 4 + r;
      if (gm < Nn) hb[(size_t)gm * 128 + n] = f2bf(z);
    }
  }
}

__global__ __launch_bounds__(512) void gmlp2_kernel(
    const unsigned short* __restrict__ hb, const int* __restrict__ row_off,
    const int* __restrict__ csr_src, const unsigned char* __restrict__ csr_ldst,
    const unsigned short* __restrict__ W3t, const float* __restrict__ b3,
    const unsigned short* __restrict__ W4t, const float* __restrict__ b4,
    float* __restrict__ out, int Nn) {
  // A2f [64][132] f32 (pad +4), aliased to bf16 rows of stride 264 ushort.
  __shared__ __align__(16) float A2f[64][132];
  __shared__ __align__(16) unsigned short Z3[64][136];
  unsigned short* A2 = (unsigned short*)&A2f[0][0];
  const int tid = threadIdx.x;
  const int bm = blockIdx.x * 64;
  const int ln = tid >> 3;
  const int cl = tid & 7;

  {  // init with own row (contiguous mapping: ch cl*8..+7 and 64+cl*8..+7)
    const int node = bm + ln;
    uint4 v0 = {0, 0, 0, 0}, v1 = {0, 0, 0, 0};
    if (node < Nn) {
      const uint4* hrow = (const uint4*)(hb + (size_t)node * 128);
      v0 = hrow[cl];
      v1 = hrow[8 + cl];
    }
    float* d0 = &A2f[ln][cl * 8];
    float* d1 = &A2f[ln][64 + cl * 8];
    d0[0] = lo2f(v0.x); d0[1] = hi2f(v0.x);
    d0[2] = lo2f(v0.y); d0[3] = hi2f(v0.y);
    d0[4] = lo2f(v0.z); d0[5] = hi2f(v0.z);
    d0[6] = lo2f(v0.w); d0[7] = hi2f(v0.w);
    d1[0] = lo2f(v1.x); d1[1] = hi2f(v1.x);
    d1[2] = lo2f(v1.y); d1[3] = hi2f(v1.y);
    d1[4] = lo2f(v1.z); d1[5] = hi2f(v1.z);
    d1[6] = lo2f(v1.w); d1[7] = hi2f(v1.w);
  }
  const int beg = row_off[bm];
  const int end = row_off[(bm + 64) < Nn ? (bm + 64) : Nn];
  __syncthreads();

  const int ldoff = bm & 255;
  const int eslot = tid >> 3;
  // edge-parallel: 64 edges per iteration, 8 threads x 32B per edge.
#pragma unroll 2
  for (int e = beg + eslot; e < end; e += 64) {
    int src = csr_src[e];
    int ld = (int)csr_ldst[e] - ldoff;
    const uint4* r = (const uint4*)(hb + (size_t)src * 128);
    uint4 u0 = r[cl], u1 = r[8 + cl];
    float* a0p = &A2f[ld][cl * 8];
    float* a1p = &A2f[ld][64 + cl * 8];
    atomicAdd(a0p + 0, lo2f(u0.x)); atomicAdd(a0p + 1, hi2f(u0.x));
    atomicAdd(a0p + 2, lo2f(u0.y)); atomicAdd(a0p + 3, hi2f(u0.y));
    atomicAdd(a0p + 4, lo2f(u0.z)); atomicAdd(a0p + 5, hi2f(u0.z));
    atomicAdd(a0p + 6, lo2f(u0.w)); atomicAdd(a0p + 7, hi2f(u0.w));
    atomicAdd(a1p + 0, lo2f(u1.x)); atomicAdd(a1p + 1, hi2f(u1.x));
    atomicAdd(a1p + 2, lo2f(u1.y)); atomicAdd(a1p + 3, hi2f(u1.y));
    atomicAdd(a1p + 4, lo2f(u1.z)); atomicAdd(a1p + 5, hi2f(u1.z));
    atomicAdd(a1p + 6, lo2f(u1.w)); atomicAdd(a1p + 7, hi2f(u1.w));
  }
  __syncthreads();

  {  // convert f32 -> bf16 in place (reg-hold, barrier, store)
    float t0[8], t1[8];
    const float* s0 = &A2f[ln][cl * 8];
    const float* s1 = &A2f[ln][64 + cl * 8];
#pragma unroll
    for (int i = 0; i < 8; ++i) t0[i] = s0[i];
#pragma unroll
    for (int i = 0; i < 8; ++i) t1[i] = s1[i];
    __syncthreads();
    unsigned short* d0 = A2 + ln * 264 + cl * 8;
    unsigned short* d1 = A2 + ln * 264 + 64 + cl * 8;
#pragma unroll
    for (int i = 0; i < 8; ++i) d0[i] = f2bf(t0[i]);
#pragma unroll
    for (int i = 0; i < 8; ++i) d1[i] = f2bf(t1[i]);
  }
  __syncthreads();

  const int lane = tid & 63;
  const int wv = tid >> 6;
  const int m0 = (wv & 3) * 16;
  const int nbase = (wv >> 2) * 64;
  const int lm = lane & 15, lq = lane >> 4;

  bf16x8 aa[4];
#pragma unroll
  for (int kt = 0; kt < 4; ++kt)
    aa[kt] = *(const bf16x8*)(A2 + (m0 + lm) * 264 + kt * 32 + lq * 8);
#pragma unroll
  for (int ntl = 0; ntl < 4; ++ntl) {
    const int n = nbase + ntl * 16 + lm;
    f32x4 acc = {0.f, 0.f, 0.f, 0.f};
#pragma unroll
    for (int kt = 0; kt < 4; ++kt) {
      bf16x8 w = *(const bf16x8*)(W3t + n * 128 + kt * 32 + lq * 8);
      acc = __builtin_amdgcn_mfma_f32_16x16x32_bf16(aa[kt], w, acc, 0, 0, 0);
    }
    const float bias = b3[n];
#pragma unroll
    for (int r = 0; r < 4; ++r) {
      float z = acc[r] + bias;
      z = z > 0.f ? z : 0.f;
      Z3[m0 + lq * 4 + r][n] = f2bf(z);
    }
  }
  __syncthreads();

  bf16x8 za[4];
#pragma unroll
  for (int kt = 0; kt < 4; ++kt)
    za[kt] = *(const bf16x8*)&Z3[m0 + lm][kt * 32 + lq * 8];
  const int nbase4 = (wv >> 2) * 32;
#pragma unroll
  for (int ntl = 0; ntl < 2; ++ntl) {
    const int n = nbase4 + ntl * 16 + lm;
    f32x4 acc = {0.f, 0.f, 0.f, 0.f};
#pragma unroll
    for (int kt = 0; kt < 4; ++kt) {
      bf16x8 w = *(const bf16x8*)(W4t + n * 128 + kt * 32 + lq * 8);
      acc = __builtin_amdgcn_mfma_f32_16x16x32_bf16(za[kt], w, acc, 0, 0, 0);
    }
    const float bias = b4[n];
#pragma unroll
    for (int r = 0; r < 4; ++r) {
      int gm = bm + m0 + lq * 4 + r;
      if (gm < Nn) out[(size_t)gm * 64 + n] = acc[r] + bias;
    }
  }
}

extern "C" void kernel_launch(void* const* d_in, const int* in_sizes, int n_in,
                              void* d_out, int out_size, void* d_ws,
                              size_t ws_size, hipStream_t stream) {
  const float* x = (const float*)d_in[0];
  const int* ei = (const int*)d_in[1];
  const float* W1 = (const float*)d_in[2];
  const float* b1 = (const float*)d_in[3];
  const float* W2 = (const float*)d_in[4];
  const float* b2 = (const float*)d_in[5];
  const float* W3 = (const float*)d_in[6];
  const float* b3 = (const float*)d_in[7];
  const float* W4 = (const float*)d_in[8];
  const float* b4 = (const float*)d_in[9];
  float* out = (float*)d_out;

  const int Nn = in_sizes[0] / 64;    // 50000
  const int E_ = in_sizes[1] / 2;     // 800000
  const int nbkt = (Nn + 255) / 256;  // 196
  const int n4 = Nn * 16;
  const int nxb = (n4 + 255) / 256;

  // workspace
  unsigned short* hb = (unsigned short*)d_ws;     // N*128
  unsigned short* xb = hb + (size_t)Nn * 128;     // N*64
  unsigned short* W1t = xb + (size_t)Nn * 64;     // 8192
  unsigned short* W2t = W1t + 8192;               // 16384
  unsigned short* W3t = W2t + 16384;              // 16384
  unsigned short* W4t = W3t + 16384;              // 8192
  int* row_off = (int*)(W4t + 8192);              // N+1
  int* csr_src = row_off + Nn + 2;                // E
  unsigned int* packed = (unsigned int*)(csr_src + E_);  // E
  int* bcnt = (int*)(packed + E_);                // 256
  int* bbase = bcnt + 256;                        // 257
  int* bcur = bbase + 260;                        // 256
  unsigned char* csr_ldst = (unsigned char*)(bcur + 256);  // E bytes

  prep_kernel<<<nxb + 192 + 1, 256, 0, stream>>>(x, xb, n4, W1, W2, W3, W4,
                                                 W1t, W2t, W3t, W4t, bcnt, nxb);
  bhist_kernel<<<(E_ + 1023) / 1024, 256, 0, stream>>>(ei, bcnt, E_, nbkt);
  bscan_kernel<<<1, 256, 0, stream>>>(bcnt, bbase, bcur, nbkt, E_);
  pass1_kernel<<<(E_ + 4095) / 4096, 512, 0, stream>>>(ei, bcur, packed, E_,
                                                       nbkt);
  pass2_kernel<<<nbkt * 4, 256, 0, stream>>>(packed, bbase, row_off, csr_src,
                                             csr_ldst, Nn, E_, nbkt);
  gmlp1_kernel<<<(Nn + 63) / 64, 512, 0, stream>>>(
      xb, row_off, csr_src, csr_ldst, W1t, b1, W2t, b2, hb, Nn);
  gmlp2_kernel<<<(Nn + 63) / 64, 512, 0, stream>>>(
      hb, row_off, csr_src, csr_ldst, W3t, b3, W4t, b4, out, Nn);
}